// Round 15
// baseline (124.394 us; speedup 1.0000x reference)
//
#include <hip/hip_runtime.h>

// GroupKAN: B=131072, F=64, G=8 x GS=8, NB=16 centers, O=64/group -> 512
// out-features, BatchNorm over batch. indices == arange(64) -> reshape.
//
// BN stats commute through the projection: pass0 accumulates per-group S1[8]
// and the symmetric second-moment triangle Mt[36] in registers, caches
// rbf_out (33.5 MB) in ws. finalize -> BN scale/shift. pass1 (kan_write_lean,
// measured 50 us = ~6.0 TB/s, roofline) streams cache -> out.
//
// R15 = R14 with the block-reduce bug fixed: 352 entries, 256 threads ->
// strided loop (R14's `if (t<352)` left entries 256..351 un-reduced; same
// bug class as round 4. Lesson: reduce loops must be count-agnostic.)

#define B_ROWS 131072
#define NFEAT  64
#define NJ     512
#define NBAS   16
#define BN_EPS 1e-5f

#define MOFF    2048          // moments: [g][44] -> 352 floats
#define RBF_OFF 4096          // rbf cache

typedef float f32x4 __attribute__((ext_vector_type(4)));

// ws float layout:
//   [1024:1536) scale   [1536:2048) shift
//   [2048:2400) moments: g*44 + k ; k<36: triangle M (s<=s'), k=36+s: S1[s]
//   [4096:4096+B*64) cached rbf_out (CACHE path)

// ---------------- pass 0: group-per-lane moments (+ rbf cache) -------------
// 512 blocks x 256 thr (4 waves). Lane l: group g=l&7, row-offset l>>3; wave
// covers 8 rows x full width contiguously. 8 iterations of 32 rows per block.
template <int CACHE>
__global__ __launch_bounds__(256, 4)
void kan_moments2(const float* __restrict__ x,
                  const float* __restrict__ centres,
                  const float* __restrict__ log_widths,
                  const float* __restrict__ rbf_w,
                  const float* __restrict__ lin_w,
                  float* __restrict__ ws)
{
    __shared__ float s_red[4][352];

    const int t   = threadIdx.x;
    const int l   = t & 63;
    const int sub = t >> 6;       // wave in block (0..3)
    const int g   = l & 7;        // group handled by this lane
    const int ro  = l >> 3;       // row offset within the wave's 8 rows

    float cc[NBAS], A[NBAS], w[NBAS];
#pragma unroll
    for (int nb = 0; nb < NBAS; ++nb) {
        cc[nb] = centres[g * NBAS + nb];
        const float is = 1.0f / (__expf(log_widths[g * NBAS + nb]) + 1e-6f);
        A[nb]  = -0.5f * is * is;
        w[nb]  = rbf_w[g * NBAS + nb];
    }
    const float lw = lin_w[g];

    float S1[8] = {0,0,0,0,0,0,0,0};
    float Mt[36];
#pragma unroll
    for (int k = 0; k < 36; ++k) Mt[k] = 0.0f;

    // rows handled: rbase + it*32, it = 0..7
    const int rbase = blockIdx.x * 256 + sub * 8 + ro;

    const float* xp0 = x + (size_t)rbase * NFEAT + g * 8;
    f32x4 v0 = *reinterpret_cast<const f32x4*>(xp0);
    f32x4 v1 = *reinterpret_cast<const f32x4*>(xp0 + 4);

    for (int it = 0; it < 8; ++it) {
        f32x4 n0, n1;
        if (it + 1 < 8) {
            const float* np = x + (size_t)(rbase + (it + 1) * 32) * NFEAT + g * 8;
            n0 = *reinterpret_cast<const f32x4*>(np);
            n1 = *reinterpret_cast<const f32x4*>(np + 4);
        }

        float r[8];
#pragma unroll
        for (int s = 0; s < 8; ++s) {
            const float xv = (s < 4) ? v0[s] : v1[s - 4];
            float acc = lw * xv;
#pragma unroll
            for (int nb = 0; nb < NBAS; ++nb) {
                const float d = xv - cc[nb];
                acc += w[nb] * __expf(A[nb] * d * d);
            }
            r[s] = acc;
        }

        if (CACHE) {
            float* cp = ws + RBF_OFF + (size_t)(rbase + it * 32) * NFEAT + g * 8;
            f32x4 c0 = {r[0], r[1], r[2], r[3]};
            f32x4 c1 = {r[4], r[5], r[6], r[7]};
            *reinterpret_cast<f32x4*>(cp)     = c0;
            *reinterpret_cast<f32x4*>(cp + 4) = c1;
        }

        // in-register moment update: zero cross-lane traffic
        int ti = 0;
#pragma unroll
        for (int s = 0; s < 8; ++s) {
            S1[s] += r[s];
#pragma unroll
            for (int sp = s; sp < 8; ++sp) {
                Mt[ti] += r[s] * r[sp];
                ++ti;
            }
        }

        v0 = n0; v1 = n1;
    }

    // butterfly across lanes sharing the same g (xor bits 3,4,5)
#pragma unroll
    for (int k = 0; k < 36; ++k) {
        float v = Mt[k];
        v += __shfl_xor(v, 8);
        v += __shfl_xor(v, 16);
        v += __shfl_xor(v, 32);
        Mt[k] = v;
    }
#pragma unroll
    for (int s = 0; s < 8; ++s) {
        float v = S1[s];
        v += __shfl_xor(v, 8);
        v += __shfl_xor(v, 16);
        v += __shfl_xor(v, 32);
        S1[s] = v;
    }

    if (l < 8) {      // lane l holds group l's wave-total
#pragma unroll
        for (int k = 0; k < 36; ++k) s_red[sub][g * 44 + k] = Mt[k];
#pragma unroll
        for (int s = 0; s < 8; ++s)  s_red[sub][g * 44 + 36 + s] = S1[s];
    }
    __syncthreads();

    // 352 entries, 256 threads -> strided (count-agnostic) reduce
    for (int idx = t; idx < 352; idx += 256) {
        float v = s_red[0][idx] + s_red[1][idx] + s_red[2][idx] + s_red[3][idx];
        atomicAdd(&ws[MOFF + idx], v);
    }
}

// ---------------- finalize: 352 moments -> scale/shift ----------------
__global__ __launch_bounds__(512)
void kan_finalize(const float* __restrict__ proj_w,
                  const float* __restrict__ proj_b,
                  const float* __restrict__ bn_gamma,
                  const float* __restrict__ bn_beta,
                  float* __restrict__ ws)
{
    const int j = threadIdx.x;      // 0..511
    const int g = j >> 6;
    const int base = MOFF + g * 44;

    double pw[8];
#pragma unroll
    for (int s = 0; s < 8; ++s) pw[s] = (double)proj_w[j * 8 + s];
    const double pb = (double)proj_b[j];

    double dotS1 = 0.0;
#pragma unroll
    for (int s = 0; s < 8; ++s)
        dotS1 += pw[s] * (double)ws[base + 36 + s];

    double q = 0.0;
    int ti = 0;
#pragma unroll
    for (int s = 0; s < 8; ++s) {
#pragma unroll
        for (int sp = s; sp < 8; ++sp) {
            const double m = (double)ws[base + ti];
            q += (s == sp ? 1.0 : 2.0) * pw[s] * pw[sp] * m;
            ++ti;
        }
    }

    const double Bd    = (double)B_ROWS;
    const double sum   = dotS1 + Bd * pb;
    const double sumsq = q + 2.0 * pb * dotS1 + Bd * pb * pb;
    const double mean  = sum / Bd;
    double var = sumsq / Bd - mean * mean;
    if (var < 0.0) var = 0.0;
    const double sc = (double)bn_gamma[j] / sqrt(var + (double)BN_EPS);
    ws[1024 + j] = (float)sc;
    ws[1536 + j] = (float)((double)bn_beta[j] - mean * sc);
}

// ---------------- pass 1: max-occupancy cached stream (measured 50 us) -----
__global__ __launch_bounds__(256, 8)
void kan_write_lean(const float* __restrict__ ws,
                    const float* __restrict__ proj_w,
                    const float* __restrict__ proj_b,
                    float* __restrict__ out)
{
    const int l     = threadIdx.x & 63;
    const int W     = (blockIdx.x * 256 + threadIdx.x) >> 6;   // 0..16383
    const int half  = W & 1;
    const int wrow  = (W >> 1) * 16;
    const int j0    = half * 256 + 4 * l;
    const int sbase = (j0 >> 6) * 8;          // slice offset within a row
    const float* rbf = ws + RBF_OFF;

    float pw[4][8], sh[4];
#pragma unroll
    for (int f = 0; f < 4; ++f) {
        const int j = j0 + f;
        const float sc = ws[1024 + j];
#pragma unroll
        for (int s = 0; s < 8; ++s) pw[f][s] = proj_w[j * 8 + s] * sc;
        sh[f] = ws[1536 + j] + proj_b[j] * sc;
    }

    for (int i = 0; i < 16; ++i) {
        const int row = wrow + i;
        const float* rp = &rbf[(size_t)row * NFEAT + sbase];
        const f32x4 a0 = *reinterpret_cast<const f32x4*>(rp);
        const f32x4 a1 = *reinterpret_cast<const f32x4*>(rp + 4);

        f32x4 ra;
#pragma unroll
        for (int f = 0; f < 4; ++f)
            ra[f] = a0[0]*pw[f][0] + a0[1]*pw[f][1] + a0[2]*pw[f][2]
                  + a0[3]*pw[f][3] + a1[0]*pw[f][4] + a1[1]*pw[f][5]
                  + a1[2]*pw[f][6] + a1[3]*pw[f][7] + sh[f];

        __builtin_nontemporal_store(ra,
            reinterpret_cast<f32x4*>(&out[(size_t)row * NJ + j0]));
    }
}

// ---------------- pass 1 fallback: recompute path (ws too small) -----------
__global__ __launch_bounds__(256)
void kan_write_rc(const float* __restrict__ x,
                  const float* __restrict__ centres,
                  const float* __restrict__ log_widths,
                  const float* __restrict__ rbf_w,
                  const float* __restrict__ lin_w,
                  const float* __restrict__ proj_w,
                  const float* __restrict__ proj_b,
                  const float* __restrict__ ws,
                  float* __restrict__ out)
{
    const int l  = threadIdx.x & 63;
    const int wv = (blockIdx.x * 256 + threadIdx.x) >> 6;
    const int g  = l >> 3;
    const int bl = (l >> 4) * 8;
    const int bh = bl + 32;

    float cc[NBAS], A[NBAS], w[NBAS];
#pragma unroll
    for (int nb = 0; nb < NBAS; ++nb) {
        cc[nb] = centres[g * NBAS + nb];
        const float is = 1.0f / (__expf(log_widths[g * NBAS + nb]) + 1e-6f);
        A[nb]  = -0.5f * is * is;
        w[nb]  = rbf_w[g * NBAS + nb];
    }
    const float lw = lin_w[g];

    float pwl[4][8], pwh[4][8], scl[4], shl[4], sch[4], shh[4];
#pragma unroll
    for (int f = 0; f < 4; ++f) {
        const int jl = 4 * l + f;
        const int jh = 256 + 4 * l + f;
#pragma unroll
        for (int s = 0; s < 8; ++s) {
            pwl[f][s] = proj_w[jl * 8 + s];
            pwh[f][s] = proj_w[jh * 8 + s];
        }
        scl[f] = ws[1024 + jl];
        shl[f] = ws[1536 + jl] + proj_b[jl] * scl[f];
        sch[f] = ws[1024 + jh];
        shh[f] = ws[1536 + jh] + proj_b[jh] * sch[f];
    }

    const int row0 = wv * 16;
    float xa = x[(size_t)row0 * NFEAT + l];
    float xb = x[(size_t)(row0 + 1) * NFEAT + l];

    for (int i = 0; i < 16; i += 2) {
        const int row = row0 + i;
        float na = 0.0f, nb2 = 0.0f;
        if (i + 2 < 16) {
            na  = x[(size_t)(row + 2) * NFEAT + l];
            nb2 = x[(size_t)(row + 3) * NFEAT + l];
        }

        float ra = lw * xa;
        float rb = lw * xb;
#pragma unroll
        for (int nb = 0; nb < NBAS; ++nb) {
            const float da = xa - cc[nb];
            const float db = xb - cc[nb];
            ra += w[nb] * __expf(A[nb] * da * da);
            rb += w[nb] * __expf(A[nb] * db * db);
        }

        float val[8], vah[8], vbl[8], vbh[8];
#pragma unroll
        for (int s = 0; s < 8; ++s) {
            val[s] = __shfl(ra, bl + s);
            vah[s] = __shfl(ra, bh + s);
            vbl[s] = __shfl(rb, bl + s);
            vbh[s] = __shfl(rb, bh + s);
        }

        f32x4 r0, r1, r2, r3;
#pragma unroll
        for (int f = 0; f < 4; ++f) {
            r0[f] = (val[0]*pwl[f][0] + val[1]*pwl[f][1] + val[2]*pwl[f][2]
                   + val[3]*pwl[f][3] + val[4]*pwl[f][4] + val[5]*pwl[f][5]
                   + val[6]*pwl[f][6] + val[7]*pwl[f][7]) * scl[f] + shl[f];
            r1[f] = (vah[0]*pwh[f][0] + vah[1]*pwh[f][1] + vah[2]*pwh[f][2]
                   + vah[3]*pwh[f][3] + vah[4]*pwh[f][4] + vah[5]*pwh[f][5]
                   + vah[6]*pwh[f][6] + vah[7]*pwh[f][7]) * sch[f] + shh[f];
            r2[f] = (vbl[0]*pwl[f][0] + vbl[1]*pwl[f][1] + vbl[2]*pwl[f][2]
                   + vbl[3]*pwl[f][3] + vbl[4]*pwl[f][4] + vbl[5]*pwl[f][5]
                   + vbl[6]*pwl[f][6] + vbl[7]*pwl[f][7]) * scl[f] + shl[f];
            r3[f] = (vbh[0]*pwh[f][0] + vbh[1]*pwh[f][1] + vbh[2]*pwh[f][2]
                   + vbh[3]*pwh[f][3] + vbh[4]*pwh[f][4] + vbh[5]*pwh[f][5]
                   + vbh[6]*pwh[f][6] + vbh[7]*pwh[f][7]) * sch[f] + shh[f];
        }

        float* oa = &out[(size_t)row * NJ];
        float* ob = &out[(size_t)(row + 1) * NJ];
        __builtin_nontemporal_store(r0, reinterpret_cast<f32x4*>(oa + 4 * l));
        __builtin_nontemporal_store(r1, reinterpret_cast<f32x4*>(oa + 256 + 4 * l));
        __builtin_nontemporal_store(r2, reinterpret_cast<f32x4*>(ob + 4 * l));
        __builtin_nontemporal_store(r3, reinterpret_cast<f32x4*>(ob + 256 + 4 * l));

        xa = na;
        xb = nb2;
    }
}

extern "C" void kernel_launch(void* const* d_in, const int* in_sizes, int n_in,
                              void* d_out, int out_size, void* d_ws, size_t ws_size,
                              hipStream_t stream)
{
    const float* x           = (const float*)d_in[0];
    const float* centres     = (const float*)d_in[1];
    const float* log_widths  = (const float*)d_in[2];
    const float* rbf_weights = (const float*)d_in[3];
    const float* linear_w    = (const float*)d_in[4];
    const float* proj_w      = (const float*)d_in[5];
    const float* proj_b      = (const float*)d_in[6];
    const float* bn_gamma    = (const float*)d_in[7];
    const float* bn_beta     = (const float*)d_in[8];
    // d_in[9] = indices: identity arange -> unused

    float* ws  = (float*)d_ws;
    float* out = (float*)d_out;

    const bool cache_ok =
        ws_size >= (size_t)(RBF_OFF + (size_t)B_ROWS * NFEAT) * sizeof(float);

    // zero scale/shift + moments
    (void)hipMemsetAsync(ws + 1024, 0, (1024 + 576) * sizeof(float), stream);

    if (cache_ok) {
        kan_moments2<1><<<512, 256, 0, stream>>>(x, centres, log_widths,
                                                 rbf_weights, linear_w, ws);
        kan_finalize<<<1, 512, 0, stream>>>(proj_w, proj_b, bn_gamma, bn_beta, ws);
        kan_write_lean<<<4096, 256, 0, stream>>>(ws, proj_w, proj_b, out);
    } else {
        kan_moments2<0><<<512, 256, 0, stream>>>(x, centres, log_widths,
                                                 rbf_weights, linear_w, ws);
        kan_finalize<<<1, 512, 0, stream>>>(proj_w, proj_b, bn_gamma, bn_beta, ws);
        kan_write_rc<<<2048, 256, 0, stream>>>(x, centres, log_widths, rbf_weights,
                                               linear_w, proj_w, proj_b, ws, out);
    }
}

// Round 16
// 100.174 us; speedup vs baseline: 1.2418x; 1.2418x over previous
//
#include <hip/hip_runtime.h>

// GroupKAN: B=131072, F=64, G=8 x GS=8, NB=16 centers, O=64/group -> 512
// out-features, BatchNorm over batch. indices == arange(64) -> reshape.
//
// BN stats commute through the projection: pass0 accumulates per-group S1[8]
// + symmetric second-moment triangle Mt[36] in registers, caches rbf_out
// (33.5 MB) in ws. finalize -> BN scale/shift. pass1 (kan_write_lean,
// measured 50 us = ~6.0 TB/s, roofline) streams cache -> out.
//
// R16 (vs R13, single variable): 16-way SPLIT moment buffers. R13's tail had
// 512 co-resident blocks atomically adding to the SAME 352 floats (~23 cache
// lines, ~8K serialized atomics/line ~= 10-15 us L2 serialization burst).
// Block b now atomics into buffer b&15 (chain 512 -> 32); finalize pre-sums
// the 16 buffers in LDS. R14/R15 lesson: launch_bounds(256,4) VGPR cap ->
// spills -> regression; moments stays 512-thr uncapped.

#define B_ROWS 131072
#define NFEAT  64
#define NJ     512
#define NBAS   16
#define BN_EPS 1e-5f

#define MOFF    2048          // 16 moment buffers: [2048 + b*352), b=0..15
#define NBUF    16
#define RBF_OFF 8192          // rbf cache

typedef float f32x4 __attribute__((ext_vector_type(4)));

// ws float layout:
//   [1024:1536) scale   [1536:2048) shift
//   [2048:7680) moment buffers: b*352 + g*44 + k ; k<36: triangle, 36+s: S1
//   [8192:8192+B*64) cached rbf_out (CACHE path)

// ---------------- pass 0: group-per-lane moments (+ rbf cache) -------------
// 512 blocks x 512 thr. Lane l: group g=l&7, row-offset l>>3; wave covers 8
// rows x full width contiguously. 4 iterations of 64 rows per block.
template <int CACHE>
__global__ __launch_bounds__(512)
void kan_moments2(const float* __restrict__ x,
                  const float* __restrict__ centres,
                  const float* __restrict__ log_widths,
                  const float* __restrict__ rbf_w,
                  const float* __restrict__ lin_w,
                  float* __restrict__ ws)
{
    __shared__ float s_red[8][352];

    const int t   = threadIdx.x;
    const int l   = t & 63;
    const int sub = t >> 6;       // wave in block (0..7)
    const int g   = l & 7;        // group handled by this lane
    const int ro  = l >> 3;       // row offset within the wave's 8 rows

    float cc[NBAS], A[NBAS], w[NBAS];
#pragma unroll
    for (int nb = 0; nb < NBAS; ++nb) {
        cc[nb] = centres[g * NBAS + nb];
        const float is = 1.0f / (__expf(log_widths[g * NBAS + nb]) + 1e-6f);
        A[nb]  = -0.5f * is * is;
        w[nb]  = rbf_w[g * NBAS + nb];
    }
    const float lw = lin_w[g];

    float S1[8] = {0,0,0,0,0,0,0,0};
    float Mt[36];
#pragma unroll
    for (int k = 0; k < 36; ++k) Mt[k] = 0.0f;

    // rows handled: rbase + it*64, it = 0..3
    const int rbase = blockIdx.x * 256 + sub * 8 + ro;

    const float* xp0 = x + (size_t)rbase * NFEAT + g * 8;
    f32x4 v0 = *reinterpret_cast<const f32x4*>(xp0);
    f32x4 v1 = *reinterpret_cast<const f32x4*>(xp0 + 4);

    for (int it = 0; it < 4; ++it) {
        f32x4 n0, n1;
        if (it + 1 < 4) {
            const float* np = x + (size_t)(rbase + (it + 1) * 64) * NFEAT + g * 8;
            n0 = *reinterpret_cast<const f32x4*>(np);
            n1 = *reinterpret_cast<const f32x4*>(np + 4);
        }

        float r[8];
#pragma unroll
        for (int s = 0; s < 8; ++s) {
            const float xv = (s < 4) ? v0[s] : v1[s - 4];
            float acc = lw * xv;
#pragma unroll
            for (int nb = 0; nb < NBAS; ++nb) {
                const float d = xv - cc[nb];
                acc += w[nb] * __expf(A[nb] * d * d);
            }
            r[s] = acc;
        }

        if (CACHE) {
            float* cp = ws + RBF_OFF + (size_t)(rbase + it * 64) * NFEAT + g * 8;
            f32x4 c0 = {r[0], r[1], r[2], r[3]};
            f32x4 c1 = {r[4], r[5], r[6], r[7]};
            *reinterpret_cast<f32x4*>(cp)     = c0;
            *reinterpret_cast<f32x4*>(cp + 4) = c1;
        }

        // in-register moment update: zero cross-lane traffic
        int ti = 0;
#pragma unroll
        for (int s = 0; s < 8; ++s) {
            S1[s] += r[s];
#pragma unroll
            for (int sp = s; sp < 8; ++sp) {
                Mt[ti] += r[s] * r[sp];
                ++ti;
            }
        }

        v0 = n0; v1 = n1;
    }

    // butterfly across lanes sharing the same g (xor bits 3,4,5)
#pragma unroll
    for (int k = 0; k < 36; ++k) {
        float v = Mt[k];
        v += __shfl_xor(v, 8);
        v += __shfl_xor(v, 16);
        v += __shfl_xor(v, 32);
        Mt[k] = v;
    }
#pragma unroll
    for (int s = 0; s < 8; ++s) {
        float v = S1[s];
        v += __shfl_xor(v, 8);
        v += __shfl_xor(v, 16);
        v += __shfl_xor(v, 32);
        S1[s] = v;
    }

    if (l < 8) {      // lane l holds group l's wave-total
#pragma unroll
        for (int k = 0; k < 36; ++k) s_red[sub][g * 44 + k] = Mt[k];
#pragma unroll
        for (int s = 0; s < 8; ++s)  s_red[sub][g * 44 + 36 + s] = S1[s];
    }
    __syncthreads();

    // 16-way split: block b -> buffer b&15 (atomic chain 512 -> 32 per addr)
    float* mbuf = ws + MOFF + (blockIdx.x & (NBUF - 1)) * 352;
    for (int idx = t; idx < 352; idx += 512) {
        float v = 0.0f;
#pragma unroll
        for (int s2 = 0; s2 < 8; ++s2) v += s_red[s2][idx];
        atomicAdd(&mbuf[idx], v);
    }
}

// ---------------- finalize: 16 buffers -> 352 moments -> scale/shift -------
__global__ __launch_bounds__(512)
void kan_finalize(const float* __restrict__ proj_w,
                  const float* __restrict__ proj_b,
                  const float* __restrict__ bn_gamma,
                  const float* __restrict__ bn_beta,
                  float* __restrict__ ws)
{
    __shared__ float s_m[352];

    const int t = threadIdx.x;

    // phase 1: sum the 16 split buffers
    for (int idx = t; idx < 352; idx += 512) {
        float v = 0.0f;
#pragma unroll
        for (int b = 0; b < NBUF; ++b) v += ws[MOFF + b * 352 + idx];
        s_m[idx] = v;
    }
    __syncthreads();

    // phase 2: per-feature scale/shift
    const int j = t;                // 0..511
    const int g = j >> 6;
    const int base = g * 44;

    double pw[8];
#pragma unroll
    for (int s = 0; s < 8; ++s) pw[s] = (double)proj_w[j * 8 + s];
    const double pb = (double)proj_b[j];

    double dotS1 = 0.0;
#pragma unroll
    for (int s = 0; s < 8; ++s)
        dotS1 += pw[s] * (double)s_m[base + 36 + s];

    double q = 0.0;
    int ti = 0;
#pragma unroll
    for (int s = 0; s < 8; ++s) {
#pragma unroll
        for (int sp = s; sp < 8; ++sp) {
            const double m = (double)s_m[base + ti];
            q += (s == sp ? 1.0 : 2.0) * pw[s] * pw[sp] * m;
            ++ti;
        }
    }

    const double Bd    = (double)B_ROWS;
    const double sum   = dotS1 + Bd * pb;
    const double sumsq = q + 2.0 * pb * dotS1 + Bd * pb * pb;
    const double mean  = sum / Bd;
    double var = sumsq / Bd - mean * mean;
    if (var < 0.0) var = 0.0;
    const double sc = (double)bn_gamma[j] / sqrt(var + (double)BN_EPS);
    ws[1024 + j] = (float)sc;
    ws[1536 + j] = (float)((double)bn_beta[j] - mean * sc);
}

// ---------------- pass 1: max-occupancy cached stream (measured 50 us) -----
__global__ __launch_bounds__(256, 8)
void kan_write_lean(const float* __restrict__ ws,
                    const float* __restrict__ proj_w,
                    const float* __restrict__ proj_b,
                    float* __restrict__ out)
{
    const int l     = threadIdx.x & 63;
    const int W     = (blockIdx.x * 256 + threadIdx.x) >> 6;   // 0..16383
    const int half  = W & 1;
    const int wrow  = (W >> 1) * 16;
    const int j0    = half * 256 + 4 * l;
    const int sbase = (j0 >> 6) * 8;          // slice offset within a row
    const float* rbf = ws + RBF_OFF;

    float pw[4][8], sh[4];
#pragma unroll
    for (int f = 0; f < 4; ++f) {
        const int j = j0 + f;
        const float sc = ws[1024 + j];
#pragma unroll
        for (int s = 0; s < 8; ++s) pw[f][s] = proj_w[j * 8 + s] * sc;
        sh[f] = ws[1536 + j] + proj_b[j] * sc;
    }

    for (int i = 0; i < 16; ++i) {
        const int row = wrow + i;
        const float* rp = &rbf[(size_t)row * NFEAT + sbase];
        const f32x4 a0 = *reinterpret_cast<const f32x4*>(rp);
        const f32x4 a1 = *reinterpret_cast<const f32x4*>(rp + 4);

        f32x4 ra;
#pragma unroll
        for (int f = 0; f < 4; ++f)
            ra[f] = a0[0]*pw[f][0] + a0[1]*pw[f][1] + a0[2]*pw[f][2]
                  + a0[3]*pw[f][3] + a1[0]*pw[f][4] + a1[1]*pw[f][5]
                  + a1[2]*pw[f][6] + a1[3]*pw[f][7] + sh[f];

        __builtin_nontemporal_store(ra,
            reinterpret_cast<f32x4*>(&out[(size_t)row * NJ + j0]));
    }
}

// ---------------- pass 1 fallback: recompute path (ws too small) -----------
__global__ __launch_bounds__(256)
void kan_write_rc(const float* __restrict__ x,
                  const float* __restrict__ centres,
                  const float* __restrict__ log_widths,
                  const float* __restrict__ rbf_w,
                  const float* __restrict__ lin_w,
                  const float* __restrict__ proj_w,
                  const float* __restrict__ proj_b,
                  const float* __restrict__ ws,
                  float* __restrict__ out)
{
    const int l  = threadIdx.x & 63;
    const int wv = (blockIdx.x * 256 + threadIdx.x) >> 6;
    const int g  = l >> 3;
    const int bl = (l >> 4) * 8;
    const int bh = bl + 32;

    float cc[NBAS], A[NBAS], w[NBAS];
#pragma unroll
    for (int nb = 0; nb < NBAS; ++nb) {
        cc[nb] = centres[g * NBAS + nb];
        const float is = 1.0f / (__expf(log_widths[g * NBAS + nb]) + 1e-6f);
        A[nb]  = -0.5f * is * is;
        w[nb]  = rbf_w[g * NBAS + nb];
    }
    const float lw = lin_w[g];

    float pwl[4][8], pwh[4][8], scl[4], shl[4], sch[4], shh[4];
#pragma unroll
    for (int f = 0; f < 4; ++f) {
        const int jl = 4 * l + f;
        const int jh = 256 + 4 * l + f;
#pragma unroll
        for (int s = 0; s < 8; ++s) {
            pwl[f][s] = proj_w[jl * 8 + s];
            pwh[f][s] = proj_w[jh * 8 + s];
        }
        scl[f] = ws[1024 + jl];
        shl[f] = ws[1536 + jl] + proj_b[jl] * scl[f];
        sch[f] = ws[1024 + jh];
        shh[f] = ws[1536 + jh] + proj_b[jh] * sch[f];
    }

    const int row0 = wv * 16;
    float xa = x[(size_t)row0 * NFEAT + l];
    float xb = x[(size_t)(row0 + 1) * NFEAT + l];

    for (int i = 0; i < 16; i += 2) {
        const int row = row0 + i;
        float na = 0.0f, nb2 = 0.0f;
        if (i + 2 < 16) {
            na  = x[(size_t)(row + 2) * NFEAT + l];
            nb2 = x[(size_t)(row + 3) * NFEAT + l];
        }

        float ra = lw * xa;
        float rb = lw * xb;
#pragma unroll
        for (int nb = 0; nb < NBAS; ++nb) {
            const float da = xa - cc[nb];
            const float db = xb - cc[nb];
            ra += w[nb] * __expf(A[nb] * da * da);
            rb += w[nb] * __expf(A[nb] * db * db);
        }

        float val[8], vah[8], vbl[8], vbh[8];
#pragma unroll
        for (int s = 0; s < 8; ++s) {
            val[s] = __shfl(ra, bl + s);
            vah[s] = __shfl(ra, bh + s);
            vbl[s] = __shfl(rb, bl + s);
            vbh[s] = __shfl(rb, bh + s);
        }

        f32x4 r0, r1, r2, r3;
#pragma unroll
        for (int f = 0; f < 4; ++f) {
            r0[f] = (val[0]*pwl[f][0] + val[1]*pwl[f][1] + val[2]*pwl[f][2]
                   + val[3]*pwl[f][3] + val[4]*pwl[f][4] + val[5]*pwl[f][5]
                   + val[6]*pwl[f][6] + val[7]*pwl[f][7]) * scl[f] + shl[f];
            r1[f] = (vah[0]*pwh[f][0] + vah[1]*pwh[f][1] + vah[2]*pwh[f][2]
                   + vah[3]*pwh[f][3] + vah[4]*pwh[f][4] + vah[5]*pwh[f][5]
                   + vah[6]*pwh[f][6] + vah[7]*pwh[f][7]) * sch[f] + shh[f];
            r2[f] = (vbl[0]*pwl[f][0] + vbl[1]*pwl[f][1] + vbl[2]*pwl[f][2]
                   + vbl[3]*pwl[f][3] + vbl[4]*pwl[f][4] + vbl[5]*pwl[f][5]
                   + vbl[6]*pwl[f][6] + vbl[7]*pwl[f][7]) * scl[f] + shl[f];
            r3[f] = (vbh[0]*pwh[f][0] + vbh[1]*pwh[f][1] + vbh[2]*pwh[f][2]
                   + vbh[3]*pwh[f][3] + vbh[4]*pwh[f][4] + vbh[5]*pwh[f][5]
                   + vbh[6]*pwh[f][6] + vbh[7]*pwh[f][7]) * sch[f] + shh[f];
        }

        float* oa = &out[(size_t)row * NJ];
        float* ob = &out[(size_t)(row + 1) * NJ];
        __builtin_nontemporal_store(r0, reinterpret_cast<f32x4*>(oa + 4 * l));
        __builtin_nontemporal_store(r1, reinterpret_cast<f32x4*>(oa + 256 + 4 * l));
        __builtin_nontemporal_store(r2, reinterpret_cast<f32x4*>(ob + 4 * l));
        __builtin_nontemporal_store(r3, reinterpret_cast<f32x4*>(ob + 256 + 4 * l));

        xa = na;
        xb = nb2;
    }
}

extern "C" void kernel_launch(void* const* d_in, const int* in_sizes, int n_in,
                              void* d_out, int out_size, void* d_ws, size_t ws_size,
                              hipStream_t stream)
{
    const float* x           = (const float*)d_in[0];
    const float* centres     = (const float*)d_in[1];
    const float* log_widths  = (const float*)d_in[2];
    const float* rbf_weights = (const float*)d_in[3];
    const float* linear_w    = (const float*)d_in[4];
    const float* proj_w      = (const float*)d_in[5];
    const float* proj_b      = (const float*)d_in[6];
    const float* bn_gamma    = (const float*)d_in[7];
    const float* bn_beta     = (const float*)d_in[8];
    // d_in[9] = indices: identity arange -> unused

    float* ws  = (float*)d_ws;
    float* out = (float*)d_out;

    const bool cache_ok =
        ws_size >= (size_t)(RBF_OFF + (size_t)B_ROWS * NFEAT) * sizeof(float);

    // zero scale/shift + the 16 moment buffers: floats [1024, 7680)
    (void)hipMemsetAsync(ws + 1024, 0, (7680 - 1024) * sizeof(float), stream);

    if (cache_ok) {
        kan_moments2<1><<<512, 512, 0, stream>>>(x, centres, log_widths,
                                                 rbf_weights, linear_w, ws);
        kan_finalize<<<1, 512, 0, stream>>>(proj_w, proj_b, bn_gamma, bn_beta, ws);
        kan_write_lean<<<4096, 256, 0, stream>>>(ws, proj_w, proj_b, out);
    } else {
        kan_moments2<0><<<512, 512, 0, stream>>>(x, centres, log_widths,
                                                 rbf_weights, linear_w, ws);
        kan_finalize<<<1, 512, 0, stream>>>(proj_w, proj_b, bn_gamma, bn_beta, ws);
        kan_write_rc<<<2048, 256, 0, stream>>>(x, centres, log_widths, rbf_weights,
                                               linear_w, proj_w, proj_b, ws, out);
    }
}

// Round 17
// 99.897 us; speedup vs baseline: 1.2452x; 1.0028x over previous
//
#include <hip/hip_runtime.h>

// GroupKAN: B=131072, F=64, G=8 x GS=8, NB=16 centers, O=64/group -> 512
// out-features, BatchNorm over batch. indices == arange(64) -> reshape.
//
// BN stats commute through the projection: pass0 accumulates per-group S1[8]
// + symmetric second-moment triangle Mt[36] in registers, caches rbf_out
// (33.5 MB) in ws. finalize -> BN scale/shift. pass1 (kan_write_lean,
// measured 50 us = ~6.0 TB/s, roofline) streams cache -> out.
//
// R17 (vs R16, moments only): WAVE-PER-GROUP layout. Wave w = group w ->
// RBF params are wave-uniform (scalar loads / readfirstlane -> SGPR), cutting
// ~50 VGPR of per-lane params. Per-thread ~85 VGPR -> 2 blocks/CU = 4
// waves/SIMD (was 1 block = 2 waves/SIMD at ~150 VGPR). Lane l owns row
// rbase+l's 8-slot group slice (contiguous 32 B, one line; waves g,g^1 share
// lines -> L1). In-register Mt outer product kept; tail = 6-step butterfly +
// lane-0 LDS deposit + R16's 16-way split atomics.

#define B_ROWS 131072
#define NFEAT  64
#define NJ     512
#define NBAS   16
#define BN_EPS 1e-5f

#define MOFF    2048          // 16 moment buffers: [2048 + b*352), b=0..15
#define NBUF    16
#define RBF_OFF 8192          // rbf cache

typedef float f32x4 __attribute__((ext_vector_type(4)));

__device__ __forceinline__ float rfl(float v) {
    return __int_as_float(__builtin_amdgcn_readfirstlane(__float_as_int(v)));
}

// ws float layout:
//   [1024:1536) scale   [1536:2048) shift
//   [2048:7680) moment buffers: b*352 + g*44 + k ; k<36: triangle, 36+s: S1
//   [8192:8192+B*64) cached rbf_out (CACHE path)

// ---------------- pass 0: wave-per-group moments (+ rbf cache) -------------
// 512 blocks x 512 thr (8 waves). Wave w handles group w; lane l handles row
// rbase + it*64 + l, slots 0..7 of its group. 4 iterations of 64 rows.
template <int CACHE>
__global__ __launch_bounds__(512)
void kan_moments3(const float* __restrict__ x,
                  const float* __restrict__ centres,
                  const float* __restrict__ log_widths,
                  const float* __restrict__ rbf_w,
                  const float* __restrict__ lin_w,
                  float* __restrict__ ws)
{
    __shared__ float s_red[352];      // 8 waves x disjoint 44-float slices

    const int t = threadIdx.x;
    const int l = t & 63;
    const int g = __builtin_amdgcn_readfirstlane(t >> 6);   // wave = group

    // params are wave-uniform: loads scalarize; computed A/lw forced to SGPR
    float cc[NBAS], A[NBAS], w[NBAS];
#pragma unroll
    for (int nb = 0; nb < NBAS; ++nb) {
        cc[nb] = centres[g * NBAS + nb];
        const float is = 1.0f / (__expf(log_widths[g * NBAS + nb]) + 1e-6f);
        A[nb]  = rfl(-0.5f * is * is);
        w[nb]  = rbf_w[g * NBAS + nb];
    }
    const float lw = rfl(lin_w[g]);

    float S1[8] = {0,0,0,0,0,0,0,0};
    float Mt[36];
#pragma unroll
    for (int k = 0; k < 36; ++k) Mt[k] = 0.0f;

    // rows handled: rbase + it*64, it = 0..3
    const int rbase = blockIdx.x * 256 + l;

    const float* xp0 = x + (size_t)rbase * NFEAT + g * 8;
    f32x4 v0 = *reinterpret_cast<const f32x4*>(xp0);
    f32x4 v1 = *reinterpret_cast<const f32x4*>(xp0 + 4);

    for (int it = 0; it < 4; ++it) {
        f32x4 n0, n1;
        if (it + 1 < 4) {
            const float* np = x + (size_t)(rbase + (it + 1) * 64) * NFEAT + g * 8;
            n0 = *reinterpret_cast<const f32x4*>(np);
            n1 = *reinterpret_cast<const f32x4*>(np + 4);
        }

        float r[8];
#pragma unroll
        for (int s = 0; s < 8; ++s) {
            const float xv = (s < 4) ? v0[s] : v1[s - 4];
            float acc = lw * xv;
#pragma unroll
            for (int nb = 0; nb < NBAS; ++nb) {
                const float d = xv - cc[nb];
                acc += w[nb] * __expf(A[nb] * d * d);
            }
            r[s] = acc;
        }

        if (CACHE) {
            float* cp = ws + RBF_OFF + (size_t)(rbase + it * 64) * NFEAT + g * 8;
            f32x4 c0 = {r[0], r[1], r[2], r[3]};
            f32x4 c1 = {r[4], r[5], r[6], r[7]};
            *reinterpret_cast<f32x4*>(cp)     = c0;
            *reinterpret_cast<f32x4*>(cp + 4) = c1;
        }

        // in-register moment update: zero cross-lane traffic
        int ti = 0;
#pragma unroll
        for (int s = 0; s < 8; ++s) {
            S1[s] += r[s];
#pragma unroll
            for (int sp = s; sp < 8; ++sp) {
                Mt[ti] += r[s] * r[sp];
                ++ti;
            }
        }

        v0 = n0; v1 = n1;
    }

    // full-wave butterfly (all 64 lanes same group)
#pragma unroll
    for (int k = 0; k < 36; ++k) {
        float v = Mt[k];
        v += __shfl_xor(v, 1);
        v += __shfl_xor(v, 2);
        v += __shfl_xor(v, 4);
        v += __shfl_xor(v, 8);
        v += __shfl_xor(v, 16);
        v += __shfl_xor(v, 32);
        Mt[k] = v;
    }
#pragma unroll
    for (int s = 0; s < 8; ++s) {
        float v = S1[s];
        v += __shfl_xor(v, 1);
        v += __shfl_xor(v, 2);
        v += __shfl_xor(v, 4);
        v += __shfl_xor(v, 8);
        v += __shfl_xor(v, 16);
        v += __shfl_xor(v, 32);
        S1[s] = v;
    }

    if (l == 0) {     // static, unrolled deposits into this wave's slice
#pragma unroll
        for (int k = 0; k < 36; ++k) s_red[g * 44 + k] = Mt[k];
#pragma unroll
        for (int s = 0; s < 8; ++s)  s_red[g * 44 + 36 + s] = S1[s];
    }
    __syncthreads();

    // 16-way split: block b -> buffer b&15 (count-agnostic strided loop)
    float* mbuf = ws + MOFF + (blockIdx.x & (NBUF - 1)) * 352;
    for (int idx = t; idx < 352; idx += 512)
        atomicAdd(&mbuf[idx], s_red[idx]);
}

// ---------------- finalize: 16 buffers -> 352 moments -> scale/shift -------
__global__ __launch_bounds__(512)
void kan_finalize(const float* __restrict__ proj_w,
                  const float* __restrict__ proj_b,
                  const float* __restrict__ bn_gamma,
                  const float* __restrict__ bn_beta,
                  float* __restrict__ ws)
{
    __shared__ float s_m[352];

    const int t = threadIdx.x;

    // phase 1: sum the 16 split buffers
    for (int idx = t; idx < 352; idx += 512) {
        float v = 0.0f;
#pragma unroll
        for (int b = 0; b < NBUF; ++b) v += ws[MOFF + b * 352 + idx];
        s_m[idx] = v;
    }
    __syncthreads();

    // phase 2: per-feature scale/shift
    const int j = t;                // 0..511
    const int g = j >> 6;
    const int base = g * 44;

    double pw[8];
#pragma unroll
    for (int s = 0; s < 8; ++s) pw[s] = (double)proj_w[j * 8 + s];
    const double pb = (double)proj_b[j];

    double dotS1 = 0.0;
#pragma unroll
    for (int s = 0; s < 8; ++s)
        dotS1 += pw[s] * (double)s_m[base + 36 + s];

    double q = 0.0;
    int ti = 0;
#pragma unroll
    for (int s = 0; s < 8; ++s) {
#pragma unroll
        for (int sp = s; sp < 8; ++sp) {
            const double m = (double)s_m[base + ti];
            q += (s == sp ? 1.0 : 2.0) * pw[s] * pw[sp] * m;
            ++ti;
        }
    }

    const double Bd    = (double)B_ROWS;
    const double sum   = dotS1 + Bd * pb;
    const double sumsq = q + 2.0 * pb * dotS1 + Bd * pb * pb;
    const double mean  = sum / Bd;
    double var = sumsq / Bd - mean * mean;
    if (var < 0.0) var = 0.0;
    const double sc = (double)bn_gamma[j] / sqrt(var + (double)BN_EPS);
    ws[1024 + j] = (float)sc;
    ws[1536 + j] = (float)((double)bn_beta[j] - mean * sc);
}

// ---------------- pass 1: max-occupancy cached stream (measured 50 us) -----
__global__ __launch_bounds__(256, 8)
void kan_write_lean(const float* __restrict__ ws,
                    const float* __restrict__ proj_w,
                    const float* __restrict__ proj_b,
                    float* __restrict__ out)
{
    const int l     = threadIdx.x & 63;
    const int W     = (blockIdx.x * 256 + threadIdx.x) >> 6;   // 0..16383
    const int half  = W & 1;
    const int wrow  = (W >> 1) * 16;
    const int j0    = half * 256 + 4 * l;
    const int sbase = (j0 >> 6) * 8;          // slice offset within a row
    const float* rbf = ws + RBF_OFF;

    float pw[4][8], sh[4];
#pragma unroll
    for (int f = 0; f < 4; ++f) {
        const int j = j0 + f;
        const float sc = ws[1024 + j];
#pragma unroll
        for (int s = 0; s < 8; ++s) pw[f][s] = proj_w[j * 8 + s] * sc;
        sh[f] = ws[1536 + j] + proj_b[j] * sc;
    }

    for (int i = 0; i < 16; ++i) {
        const int row = wrow + i;
        const float* rp = &rbf[(size_t)row * NFEAT + sbase];
        const f32x4 a0 = *reinterpret_cast<const f32x4*>(rp);
        const f32x4 a1 = *reinterpret_cast<const f32x4*>(rp + 4);

        f32x4 ra;
#pragma unroll
        for (int f = 0; f < 4; ++f)
            ra[f] = a0[0]*pw[f][0] + a0[1]*pw[f][1] + a0[2]*pw[f][2]
                  + a0[3]*pw[f][3] + a1[0]*pw[f][4] + a1[1]*pw[f][5]
                  + a1[2]*pw[f][6] + a1[3]*pw[f][7] + sh[f];

        __builtin_nontemporal_store(ra,
            reinterpret_cast<f32x4*>(&out[(size_t)row * NJ + j0]));
    }
}

// ---------------- pass 1 fallback: recompute path (ws too small) -----------
__global__ __launch_bounds__(256)
void kan_write_rc(const float* __restrict__ x,
                  const float* __restrict__ centres,
                  const float* __restrict__ log_widths,
                  const float* __restrict__ rbf_w,
                  const float* __restrict__ lin_w,
                  const float* __restrict__ proj_w,
                  const float* __restrict__ proj_b,
                  const float* __restrict__ ws,
                  float* __restrict__ out)
{
    const int l  = threadIdx.x & 63;
    const int wv = (blockIdx.x * 256 + threadIdx.x) >> 6;
    const int g  = l >> 3;
    const int bl = (l >> 4) * 8;
    const int bh = bl + 32;

    float cc[NBAS], A[NBAS], w[NBAS];
#pragma unroll
    for (int nb = 0; nb < NBAS; ++nb) {
        cc[nb] = centres[g * NBAS + nb];
        const float is = 1.0f / (__expf(log_widths[g * NBAS + nb]) + 1e-6f);
        A[nb]  = -0.5f * is * is;
        w[nb]  = rbf_w[g * NBAS + nb];
    }
    const float lw = lin_w[g];

    float pwl[4][8], pwh[4][8], scl[4], shl[4], sch[4], shh[4];
#pragma unroll
    for (int f = 0; f < 4; ++f) {
        const int jl = 4 * l + f;
        const int jh = 256 + 4 * l + f;
#pragma unroll
        for (int s = 0; s < 8; ++s) {
            pwl[f][s] = proj_w[jl * 8 + s];
            pwh[f][s] = proj_w[jh * 8 + s];
        }
        scl[f] = ws[1024 + jl];
        shl[f] = ws[1536 + jl] + proj_b[jl] * scl[f];
        sch[f] = ws[1024 + jh];
        shh[f] = ws[1536 + jh] + proj_b[jh] * sch[f];
    }

    const int row0 = wv * 16;
    float xa = x[(size_t)row0 * NFEAT + l];
    float xb = x[(size_t)(row0 + 1) * NFEAT + l];

    for (int i = 0; i < 16; i += 2) {
        const int row = row0 + i;
        float na = 0.0f, nb2 = 0.0f;
        if (i + 2 < 16) {
            na  = x[(size_t)(row + 2) * NFEAT + l];
            nb2 = x[(size_t)(row + 3) * NFEAT + l];
        }

        float ra = lw * xa;
        float rb = lw * xb;
#pragma unroll
        for (int nb = 0; nb < NBAS; ++nb) {
            const float da = xa - cc[nb];
            const float db = xb - cc[nb];
            ra += w[nb] * __expf(A[nb] * da * da);
            rb += w[nb] * __expf(A[nb] * db * db);
        }

        float val[8], vah[8], vbl[8], vbh[8];
#pragma unroll
        for (int s = 0; s < 8; ++s) {
            val[s] = __shfl(ra, bl + s);
            vah[s] = __shfl(ra, bh + s);
            vbl[s] = __shfl(rb, bl + s);
            vbh[s] = __shfl(rb, bh + s);
        }

        f32x4 r0, r1, r2, r3;
#pragma unroll
        for (int f = 0; f < 4; ++f) {
            r0[f] = (val[0]*pwl[f][0] + val[1]*pwl[f][1] + val[2]*pwl[f][2]
                   + val[3]*pwl[f][3] + val[4]*pwl[f][4] + val[5]*pwl[f][5]
                   + val[6]*pwl[f][6] + val[7]*pwl[f][7]) * scl[f] + shl[f];
            r1[f] = (vah[0]*pwh[f][0] + vah[1]*pwh[f][1] + vah[2]*pwh[f][2]
                   + vah[3]*pwh[f][3] + vah[4]*pwh[f][4] + vah[5]*pwh[f][5]
                   + vah[6]*pwh[f][6] + vah[7]*pwh[f][7]) * sch[f] + shh[f];
            r2[f] = (vbl[0]*pwl[f][0] + vbl[1]*pwl[f][1] + vbl[2]*pwl[f][2]
                   + vbl[3]*pwl[f][3] + vbl[4]*pwl[f][4] + vbl[5]*pwl[f][5]
                   + vbl[6]*pwl[f][6] + vbl[7]*pwl[f][7]) * scl[f] + shl[f];
            r3[f] = (vbh[0]*pwh[f][0] + vbh[1]*pwh[f][1] + vbh[2]*pwh[f][2]
                   + vbh[3]*pwh[f][3] + vbh[4]*pwh[f][4] + vbh[5]*pwh[f][5]
                   + vbh[6]*pwh[f][6] + vbh[7]*pwh[f][7]) * sch[f] + shh[f];
        }

        float* oa = &out[(size_t)row * NJ];
        float* ob = &out[(size_t)(row + 1) * NJ];
        __builtin_nontemporal_store(r0, reinterpret_cast<f32x4*>(oa + 4 * l));
        __builtin_nontemporal_store(r1, reinterpret_cast<f32x4*>(oa + 256 + 4 * l));
        __builtin_nontemporal_store(r2, reinterpret_cast<f32x4*>(ob + 4 * l));
        __builtin_nontemporal_store(r3, reinterpret_cast<f32x4*>(ob + 256 + 4 * l));

        xa = na;
        xb = nb2;
    }
}

extern "C" void kernel_launch(void* const* d_in, const int* in_sizes, int n_in,
                              void* d_out, int out_size, void* d_ws, size_t ws_size,
                              hipStream_t stream)
{
    const float* x           = (const float*)d_in[0];
    const float* centres     = (const float*)d_in[1];
    const float* log_widths  = (const float*)d_in[2];
    const float* rbf_weights = (const float*)d_in[3];
    const float* linear_w    = (const float*)d_in[4];
    const float* proj_w      = (const float*)d_in[5];
    const float* proj_b      = (const float*)d_in[6];
    const float* bn_gamma    = (const float*)d_in[7];
    const float* bn_beta     = (const float*)d_in[8];
    // d_in[9] = indices: identity arange -> unused

    float* ws  = (float*)d_ws;
    float* out = (float*)d_out;

    const bool cache_ok =
        ws_size >= (size_t)(RBF_OFF + (size_t)B_ROWS * NFEAT) * sizeof(float);

    // zero scale/shift + the 16 moment buffers: floats [1024, 7680)
    (void)hipMemsetAsync(ws + 1024, 0, (7680 - 1024) * sizeof(float), stream);

    if (cache_ok) {
        kan_moments3<1><<<512, 512, 0, stream>>>(x, centres, log_widths,
                                                 rbf_weights, linear_w, ws);
        kan_finalize<<<1, 512, 0, stream>>>(proj_w, proj_b, bn_gamma, bn_beta, ws);
        kan_write_lean<<<4096, 256, 0, stream>>>(ws, proj_w, proj_b, out);
    } else {
        kan_moments3<0><<<512, 512, 0, stream>>>(x, centres, log_widths,
                                                 rbf_weights, linear_w, ws);
        kan_finalize<<<1, 512, 0, stream>>>(proj_w, proj_b, bn_gamma, bn_beta, ws);
        kan_write_rc<<<2048, 256, 0, stream>>>(x, centres, log_widths, rbf_weights,
                                               linear_w, proj_w, proj_b, ws, out);
    }
}